// Round 1
// 9106.730 us; speedup vs baseline: 2.2022x; 2.2022x over previous
//
#include <hip/hip_runtime.h>
#include <math.h>

// ---------------- problem constants ----------------
#define TDIM 1024          // T
#define DDIM 1024          // D (= H*HD)
#define NH   16
#define HDIM 64
#define BB   4
#define NLAYER 6
#define NTOK (BB*TDIM)     // 4096 rows
#define NELEM (NTOK*DDIM)  // 4,194,304

// ---------------- embedding: x = tok[idx] + pos ----------------
__global__ __launch_bounds__(256)
void k_embed(const int* __restrict__ idx, const float* __restrict__ tok,
             const float* __restrict__ pos, float* __restrict__ x) {
  int e4 = blockIdx.x * 256 + threadIdx.x;   // 1M threads, 4 elems each
  int e  = e4 * 4;
  int r  = e >> 10;            // token row 0..4095
  int d  = e & 1023;
  int tp = r & (TDIM - 1);     // position within sequence
  int id = idx[r];
  float4 a = *reinterpret_cast<const float4*>(&tok[(size_t)id * DDIM + d]);
  float4 p = *reinterpret_cast<const float4*>(&pos[(size_t)tp * DDIM + d]);
  float4 o = make_float4(a.x + p.x, a.y + p.y, a.z + p.z, a.w + p.w);
  reinterpret_cast<float4*>(x)[e4] = o;
}

// ---------------- full-tensor layernorm: 2-stage fp64 reduction ----------------
__global__ __launch_bounds__(256)
void k_reduce1(const float* __restrict__ x, double* __restrict__ part) {
  int t = threadIdx.x;
  size_t base = (size_t)blockIdx.x * 1024;
  double s = 0.0, ss = 0.0;
  #pragma unroll
  for (int it = 0; it < 4; ++it) {
    double v = (double)x[base + it * 256 + t];
    s += v; ss += v * v;
  }
  __shared__ double rs[256], rq[256];
  rs[t] = s; rq[t] = ss; __syncthreads();
  for (int w = 128; w > 0; w >>= 1) {
    if (t < w) { rs[t] += rs[t + w]; rq[t] += rq[t + w]; }
    __syncthreads();
  }
  if (t == 0) { part[blockIdx.x * 2] = rs[0]; part[blockIdx.x * 2 + 1] = rq[0]; }
}

__global__ __launch_bounds__(1024)
void k_reduce2(const double* __restrict__ part, double* __restrict__ stats) {
  int t = threadIdx.x;
  double s = 0.0, ss = 0.0;
  #pragma unroll
  for (int it = 0; it < 4; ++it) {
    int p = it * 1024 + t;
    s  += part[p * 2];
    ss += part[p * 2 + 1];
  }
  __shared__ double rs[1024], rq[1024];
  rs[t] = s; rq[t] = ss; __syncthreads();
  for (int w = 512; w > 0; w >>= 1) {
    if (t < w) { rs[t] += rs[t + w]; rq[t] += rq[t + w]; }
    __syncthreads();
  }
  if (t == 0) {
    double mu  = rs[0] / (double)NELEM;
    double var = rq[0] / (double)NELEM - mu * mu;
    stats[0] = mu;
    stats[1] = 1.0 / sqrt(var + 1e-5);
  }
}

__global__ __launch_bounds__(256)
void k_norm4(const float* __restrict__ x, const double* __restrict__ stats,
             float* __restrict__ y) {
  int e4 = blockIdx.x * 256 + threadIdx.x;
  double mu = stats[0], rs = stats[1];
  float4 v = reinterpret_cast<const float4*>(x)[e4];
  float4 o = make_float4((float)(((double)v.x - mu) * rs),
                         (float)(((double)v.y - mu) * rs),
                         (float)(((double)v.z - mu) * rs),
                         (float)(((double)v.w - mu) * rs));
  reinterpret_cast<float4*>(y)[e4] = o;
}

// t1 += proj (in place)
__global__ __launch_bounds__(256)
void k_add4(float* __restrict__ t1, const float* __restrict__ proj) {
  int e4 = blockIdx.x * 256 + threadIdx.x;
  float4 a = reinterpret_cast<const float4*>(t1)[e4];
  float4 b = reinterpret_cast<const float4*>(proj)[e4];
  float4 o = make_float4(a.x + b.x, a.y + b.y, a.z + b.z, a.w + b.w);
  reinterpret_cast<float4*>(t1)[e4] = o;
}

// x = 2*((t1 - mu)*rstd + proj)
__global__ __launch_bounds__(256)
void k_combine4(const float* __restrict__ t1, const float* __restrict__ proj,
                const double* __restrict__ stats, float* __restrict__ x) {
  int e4 = blockIdx.x * 256 + threadIdx.x;
  double mu = stats[0], rs = stats[1];
  float4 a = reinterpret_cast<const float4*>(t1)[e4];
  float4 b = reinterpret_cast<const float4*>(proj)[e4];
  float4 o = make_float4((float)(2.0 * (((double)a.x - mu) * rs + (double)b.x)),
                         (float)(2.0 * (((double)a.y - mu) * rs + (double)b.y)),
                         (float)(2.0 * (((double)a.z - mu) * rs + (double)b.z)),
                         (float)(2.0 * (((double)a.w - mu) * rs + (double)b.w)));
  reinterpret_cast<float4*>(x)[e4] = o;
}

// out_fp32 = (x - mu)*rstd
__global__ __launch_bounds__(256)
void k_norm_out(const float* __restrict__ x, const double* __restrict__ stats,
                float* __restrict__ out) {
  int e4 = blockIdx.x * 256 + threadIdx.x;
  double mu = stats[0], rs = stats[1];
  float4 v = reinterpret_cast<const float4*>(x)[e4];
  float4 o = make_float4((float)(((double)v.x - mu) * rs),
                         (float)(((double)v.y - mu) * rs),
                         (float)(((double)v.z - mu) * rs),
                         (float)(((double)v.w - mu) * rs));
  reinterpret_cast<float4*>(out)[e4] = o;
}

// ---------------- GEMM (fp32 in, fp64 accumulate): C = A[4096x1024] * B[1024x1024] ----
// 64x64 tile, BK=16, 256 threads, 4x4/thread.
// scatter=1: write C to [B,H,T,HD] layout (for q/k/v); scatter=0: plain row-major.
__global__ __launch_bounds__(256)
void k_gemm(const float* __restrict__ A, const float* __restrict__ Bm,
            float* __restrict__ C, int scatter) {
  __shared__ float As[16][64];
  __shared__ float Bs[16][64];
  int t  = threadIdx.x;
  int m0 = blockIdx.y * 64;
  int n0 = blockIdx.x * 64;
  int tx = t & 15, ty = t >> 4;
  int ar = t >> 2;            // A tile row 0..63
  int ak = (t & 3) * 4;       // A tile k-chunk
  int br = t >> 4;            // B tile k-row 0..15
  int bc = (t & 15) * 4;      // B tile col-chunk
  double acc[4][4] = {};

  for (int kk = 0; kk < DDIM; kk += 16) {
    float4 av = *reinterpret_cast<const float4*>(&A[(size_t)(m0 + ar) * DDIM + kk + ak]);
    float4 bv = *reinterpret_cast<const float4*>(&Bm[(size_t)(kk + br) * DDIM + n0 + bc]);
    __syncthreads();
    As[ak + 0][ar] = av.x; As[ak + 1][ar] = av.y;
    As[ak + 2][ar] = av.z; As[ak + 3][ar] = av.w;
    Bs[br][bc + 0] = bv.x; Bs[br][bc + 1] = bv.y;
    Bs[br][bc + 2] = bv.z; Bs[br][bc + 3] = bv.w;
    __syncthreads();
    #pragma unroll
    for (int k = 0; k < 16; ++k) {
      float4 a4 = *reinterpret_cast<const float4*>(&As[k][ty * 4]);
      float4 b4 = *reinterpret_cast<const float4*>(&Bs[k][tx * 4]);
      double ad[4] = {(double)a4.x, (double)a4.y, (double)a4.z, (double)a4.w};
      double bd[4] = {(double)b4.x, (double)b4.y, (double)b4.z, (double)b4.w};
      #pragma unroll
      for (int i = 0; i < 4; ++i)
        #pragma unroll
        for (int j = 0; j < 4; ++j)
          acc[i][j] += ad[i] * bd[j];
    }
  }

  #pragma unroll
  for (int i = 0; i < 4; ++i) {
    int r  = m0 + ty * 4 + i;
    int b  = r >> 10;           // batch
    int tp = r & 1023;          // seq pos
    #pragma unroll
    for (int j = 0; j < 4; ++j) {
      int c = n0 + tx * 4 + j;
      float val = (float)acc[i][j];
      if (scatter) {
        int h = c >> 6, d = c & 63;
        C[((size_t)((b * NH + h) * TDIM + tp)) * HDIM + d] = val;
      } else {
        C[(size_t)r * DDIM + c] = val;
      }
    }
  }
}

// ---------------- attention: tiled flash-style, fp64 accumulate ----------------
// Transposed-score variant: for output row i, "query" = k[i], keys = q[j], values = v[j],
// j <= i.  One block per (b,h, 64-row i-tile).  GEMM-style 4x4 register blocking for
// both S = K_i . Q_j^T and O += P . V_j; online softmax in fp64 (order-compatible with
// the previous 2-pass fp64 kernel: identical d-summation order, global row max).
// P round-trips through LDS as fp32 (<=1e-7 rel; all accumulation stays fp64).
__global__ __launch_bounds__(256)
void k_attn_flash(const float* __restrict__ q, const float* __restrict__ k,
                  const float* __restrict__ v, float* __restrict__ attout) {
  int it = blockIdx.x;           // i-tile index 0..15
  int bh = blockIdx.y;           // b*16 + h
  int b  = bh >> 4, h = bh & 15;
  const float* qh = q + (size_t)bh * TDIM * HDIM;
  const float* kh = k + (size_t)bh * TDIM * HDIM;
  const float* vh = v + (size_t)bh * TDIM * HDIM;
  int i0 = it * 64;

  // pad 68 floats: keeps float4 alignment (272 B % 16 == 0) and breaks bank conflicts
  __shared__ float Ks[64][68];   // K tile, transposed: Ks[d][i]
  __shared__ float Qs[64][68];   // Q tile, transposed: Qs[d][j]; reused as Pt[j][i]
  __shared__ float Vs[64][68];   // V tile, row-major:  Vs[j][d]

  int t  = threadIdx.x;
  int tx = t & 15, ty = t >> 4;  // thread owns i-rows ty*4+., cols tx*4+.

  // ---- stage K tile (transposed) once ----
  #pragma unroll
  for (int itr = 0; itr < 4; ++itr) {
    int f = t + 256 * itr;
    int r = f >> 4, dc = (f & 15) * 4;
    float4 val = *reinterpret_cast<const float4*>(&kh[(size_t)(i0 + r) * HDIM + dc]);
    Ks[dc + 0][r] = val.x; Ks[dc + 1][r] = val.y;
    Ks[dc + 2][r] = val.z; Ks[dc + 3][r] = val.w;
  }

  double O[4][4] = {};
  double m[4], l[4];
  #pragma unroll
  for (int i = 0; i < 4; ++i) { m[i] = -1.0e300; l[i] = 0.0; }

  for (int jt = 0; jt <= it; ++jt) {
    int j0 = jt * 64;

    // ---- load Q,V tiles to regs (global, coalesced float4) ----
    float4 qv[4], vv[4];
    #pragma unroll
    for (int itr = 0; itr < 4; ++itr) {
      int f = t + 256 * itr;
      int r = f >> 4, dc = (f & 15) * 4;
      qv[itr] = *reinterpret_cast<const float4*>(&qh[(size_t)(j0 + r) * HDIM + dc]);
      vv[itr] = *reinterpret_cast<const float4*>(&vh[(size_t)(j0 + r) * HDIM + dc]);
    }
    __syncthreads();             // prev iteration's PV reads (Pt=Qs, Vs) done; Ks staged
    #pragma unroll
    for (int itr = 0; itr < 4; ++itr) {
      int f = t + 256 * itr;
      int r = f >> 4, dc = (f & 15) * 4;
      Qs[dc + 0][r] = qv[itr].x; Qs[dc + 1][r] = qv[itr].y;
      Qs[dc + 2][r] = qv[itr].z; Qs[dc + 3][r] = qv[itr].w;
      *reinterpret_cast<float4*>(&Vs[r][dc]) = vv[itr];
    }
    __syncthreads();

    // ---- S[4][4] = K_i . Q_j^T  (fp64, d ascending: same order as old kernel) ----
    double S[4][4] = {};
    #pragma unroll 16
    for (int d = 0; d < 64; ++d) {
      float4 kf = *reinterpret_cast<const float4*>(&Ks[d][ty * 4]);
      float4 qf = *reinterpret_cast<const float4*>(&Qs[d][tx * 4]);
      double kd[4] = {(double)kf.x, (double)kf.y, (double)kf.z, (double)kf.w};
      double qd[4] = {(double)qf.x, (double)qf.y, (double)qf.z, (double)qf.w};
      #pragma unroll
      for (int i = 0; i < 4; ++i)
        #pragma unroll
        for (int j = 0; j < 4; ++j)
          S[i][j] += kd[i] * qd[j];
    }

    // ---- scale + causal mask (diagonal tile only) ----
    double mloc[4];
    #pragma unroll
    for (int i = 0; i < 4; ++i) {
      #pragma unroll
      for (int j = 0; j < 4; ++j) {
        S[i][j] *= 0.125;
        if (jt == it && (tx * 4 + j) > (ty * 4 + i)) S[i][j] = -1.0e300;
      }
      mloc[i] = fmax(fmax(S[i][0], S[i][1]), fmax(S[i][2], S[i][3]));
    }
    // row max across the 16 tx-lanes (xor 1,2,4,8 flips tx bits only)
    #pragma unroll
    for (int xm = 1; xm < 16; xm <<= 1)
      #pragma unroll
      for (int i = 0; i < 4; ++i)
        mloc[i] = fmax(mloc[i], __shfl_xor(mloc[i], xm, 64));

    // ---- online softmax update (fp64) ----
    double p[4][4], tsum[4];
    #pragma unroll
    for (int i = 0; i < 4; ++i) {
      double mnew  = fmax(m[i], mloc[i]);
      double scale = exp(m[i] - mnew);
      m[i] = mnew;
      tsum[i] = 0.0;
      #pragma unroll
      for (int j = 0; j < 4; ++j) {
        p[i][j] = exp(S[i][j] - mnew);
        tsum[i] += p[i][j];
      }
      l[i] *= scale;
      #pragma unroll
      for (int j = 0; j < 4; ++j) O[i][j] *= scale;
    }
    #pragma unroll
    for (int xm = 1; xm < 16; xm <<= 1)
      #pragma unroll
      for (int i = 0; i < 4; ++i)
        tsum[i] += __shfl_xor(tsum[i], xm, 64);
    #pragma unroll
    for (int i = 0; i < 4; ++i) l[i] += tsum[i];

    __syncthreads();             // everyone done reading Qs; safe to overwrite with Pt
    // Pt[j][i] = p[i][j]  (fp32, aliases Qs)
    #pragma unroll
    for (int i = 0; i < 4; ++i)
      #pragma unroll
      for (int j = 0; j < 4; ++j)
        Qs[tx * 4 + j][ty * 4 + i] = (float)p[i][j];
    __syncthreads();

    // ---- O[4][4] += P . V  (fp64 accumulate) ----
    #pragma unroll 16
    for (int jl = 0; jl < 64; ++jl) {
      float4 pf = *reinterpret_cast<const float4*>(&Qs[jl][ty * 4]);
      float4 vf = *reinterpret_cast<const float4*>(&Vs[jl][tx * 4]);
      double pd[4] = {(double)pf.x, (double)pf.y, (double)pf.z, (double)pf.w};
      double vd[4] = {(double)vf.x, (double)vf.y, (double)vf.z, (double)vf.w};
      #pragma unroll
      for (int i = 0; i < 4; ++i)
        #pragma unroll
        for (int j = 0; j < 4; ++j)
          O[i][j] += pd[i] * vd[j];
    }
  }

  // ---- epilogue: out[b, i, h*64 + d] = O / l ----
  #pragma unroll
  for (int i = 0; i < 4; ++i) {
    int ig = i0 + ty * 4 + i;
    double inv = 1.0 / l[i];
    float4 o;
    o.x = (float)(O[i][0] * inv); o.y = (float)(O[i][1] * inv);
    o.z = (float)(O[i][2] * inv); o.w = (float)(O[i][3] * inv);
    *reinterpret_cast<float4*>(
        &attout[((size_t)(b * TDIM + ig)) * DDIM + h * HDIM + tx * 4]) = o;
  }
}

// ---------------- launcher ----------------
extern "C" void kernel_launch(void* const* d_in, const int* in_sizes, int n_in,
                              void* d_out, int out_size, void* d_ws, size_t ws_size,
                              hipStream_t stream) {
  (void)in_sizes; (void)n_in; (void)out_size; (void)ws_size;
  const int*   idx = (const int*)d_in[0];
  const float* tok = (const float*)d_in[1];
  const float* pos = (const float*)d_in[2];
  const float* wq  = (const float*)d_in[3];
  const float* wk  = (const float*)d_in[4];
  const float* wv  = (const float*)d_in[5];
  const float* wo  = (const float*)d_in[6];
  // d_in[7..9] (w_in, w_out, lm_head) are dead code in the reference
  float* out = (float*)d_out;

  float* ws   = (float*)d_ws;
  float* x    = ws;                 // [4096,1024]; also reused for att
  float* xn   = x   + NELEM;        // [4096,1024]  (also t1 = xn+proj)
  float* q    = xn  + NELEM;        // [B,H,T,HD]   (also reused for proj)
  float* k    = q   + NELEM;        // [B,H,T,HD]
  float* v    = k   + NELEM;        // [B,H,T,HD]
  float* att  = x;                  // alias: x dead between norm(x) and combine
  float* proj = q;                  // alias: q dead once att computed
  double* part  = (double*)(v + NELEM);   // [4096*2] fp64 partials (64 KB)
  double* stats = part + 8192;            // [2] fp64 (mu, rstd)

  dim3 ggemm(DDIM / 64, NTOK / 64);   // (16, 64)
  dim3 gattn(TDIM / 64, BB * NH);     // (16, 64) — one block per (bh, i-tile)

  k_embed<<<4096, 256, 0, stream>>>(idx, tok, pos, x);

  for (int l = 0; l < NLAYER; ++l) {
    // xn = ln_all(x)
    k_reduce1<<<4096, 256, 0, stream>>>(x, part);
    k_reduce2<<<1, 1024, 0, stream>>>(part, stats);
    k_norm4<<<4096, 256, 0, stream>>>(x, stats, xn);
    // q,k,v (scattered to [B,H,T,HD])
    k_gemm<<<ggemm, 256, 0, stream>>>(xn, wq, q, 1);
    k_gemm<<<ggemm, 256, 0, stream>>>(xn, wk, k, 1);
    k_gemm<<<ggemm, 256, 0, stream>>>(xn, wv, v, 1);
    // attention -> att [4096,1024] (x-alias; x is dead here)
    k_attn_flash<<<gattn, 256, 0, stream>>>(q, k, v, att);
    // proj = att @ Wo   (plain layout; writes into q-alias)
    k_gemm<<<ggemm, 256, 0, stream>>>(att, wo, proj, 0);
    // t1 = xn + proj (in place in xn)
    k_add4<<<4096, 256, 0, stream>>>(xn, proj);
    // x = 2*(ln_all(t1) + proj)
    k_reduce1<<<4096, 256, 0, stream>>>(xn, part);
    k_reduce2<<<1, 1024, 0, stream>>>(part, stats);
    k_combine4<<<4096, 256, 0, stream>>>(xn, proj, stats, x);
  }

  // out = fp32(ln_all(x))
  k_reduce1<<<4096, 256, 0, stream>>>(x, part);
  k_reduce2<<<1, 1024, 0, stream>>>(part, stats);
  k_norm_out<<<4096, 256, 0, stream>>>(x, stats, out);
}

// Round 3
// 7896.092 us; speedup vs baseline: 2.5399x; 1.1533x over previous
//
#include <hip/hip_runtime.h>
#include <math.h>

// ---------------- problem constants ----------------
#define TDIM 1024          // T
#define DDIM 1024          // D (= H*HD)
#define NH   16
#define HDIM 64
#define BB   4
#define NLAYER 6
#define NTOK (BB*TDIM)     // 4096 rows
#define NELEM (NTOK*DDIM)  // 4,194,304

// ---------------- embedding: x = tok[idx] + pos ----------------
__global__ __launch_bounds__(256)
void k_embed(const int* __restrict__ idx, const float* __restrict__ tok,
             const float* __restrict__ pos, float* __restrict__ x) {
  int e4 = blockIdx.x * 256 + threadIdx.x;   // 1M threads, 4 elems each
  int e  = e4 * 4;
  int r  = e >> 10;            // token row 0..4095
  int d  = e & 1023;
  int tp = r & (TDIM - 1);     // position within sequence
  int id = idx[r];
  float4 a = *reinterpret_cast<const float4*>(&tok[(size_t)id * DDIM + d]);
  float4 p = *reinterpret_cast<const float4*>(&pos[(size_t)tp * DDIM + d]);
  float4 o = make_float4(a.x + p.x, a.y + p.y, a.z + p.z, a.w + p.w);
  reinterpret_cast<float4*>(x)[e4] = o;
}

// ---------------- full-tensor layernorm: 2-stage fp64 reduction ----------------
__global__ __launch_bounds__(256)
void k_reduce1(const float* __restrict__ x, double* __restrict__ part) {
  int t = threadIdx.x;
  size_t base = (size_t)blockIdx.x * 1024;
  double s = 0.0, ss = 0.0;
  #pragma unroll
  for (int it = 0; it < 4; ++it) {
    double v = (double)x[base + it * 256 + t];
    s += v; ss += v * v;
  }
  __shared__ double rs[256], rq[256];
  rs[t] = s; rq[t] = ss; __syncthreads();
  for (int w = 128; w > 0; w >>= 1) {
    if (t < w) { rs[t] += rs[t + w]; rq[t] += rq[t + w]; }
    __syncthreads();
  }
  if (t == 0) { part[blockIdx.x * 2] = rs[0]; part[blockIdx.x * 2 + 1] = rq[0]; }
}

__global__ __launch_bounds__(1024)
void k_reduce2(const double* __restrict__ part, double* __restrict__ stats) {
  int t = threadIdx.x;
  double s = 0.0, ss = 0.0;
  #pragma unroll
  for (int it = 0; it < 4; ++it) {
    int p = it * 1024 + t;
    s  += part[p * 2];
    ss += part[p * 2 + 1];
  }
  __shared__ double rs[1024], rq[1024];
  rs[t] = s; rq[t] = ss; __syncthreads();
  for (int w = 512; w > 0; w >>= 1) {
    if (t < w) { rs[t] += rs[t + w]; rq[t] += rq[t + w]; }
    __syncthreads();
  }
  if (t == 0) {
    double mu  = rs[0] / (double)NELEM;
    double var = rq[0] / (double)NELEM - mu * mu;
    stats[0] = mu;
    stats[1] = 1.0 / sqrt(var + 1e-5);
  }
}

__global__ __launch_bounds__(256)
void k_norm4(const float* __restrict__ x, const double* __restrict__ stats,
             float* __restrict__ y) {
  int e4 = blockIdx.x * 256 + threadIdx.x;
  double mu = stats[0], rs = stats[1];
  float4 v = reinterpret_cast<const float4*>(x)[e4];
  float4 o = make_float4((float)(((double)v.x - mu) * rs),
                         (float)(((double)v.y - mu) * rs),
                         (float)(((double)v.z - mu) * rs),
                         (float)(((double)v.w - mu) * rs));
  reinterpret_cast<float4*>(y)[e4] = o;
}

// t1 += proj (in place)
__global__ __launch_bounds__(256)
void k_add4(float* __restrict__ t1, const float* __restrict__ proj) {
  int e4 = blockIdx.x * 256 + threadIdx.x;
  float4 a = reinterpret_cast<const float4*>(t1)[e4];
  float4 b = reinterpret_cast<const float4*>(proj)[e4];
  float4 o = make_float4(a.x + b.x, a.y + b.y, a.z + b.z, a.w + b.w);
  reinterpret_cast<float4*>(t1)[e4] = o;
}

// x = 2*((t1 - mu)*rstd + proj)
__global__ __launch_bounds__(256)
void k_combine4(const float* __restrict__ t1, const float* __restrict__ proj,
                const double* __restrict__ stats, float* __restrict__ x) {
  int e4 = blockIdx.x * 256 + threadIdx.x;
  double mu = stats[0], rs = stats[1];
  float4 a = reinterpret_cast<const float4*>(t1)[e4];
  float4 b = reinterpret_cast<const float4*>(proj)[e4];
  float4 o = make_float4((float)(2.0 * (((double)a.x - mu) * rs + (double)b.x)),
                         (float)(2.0 * (((double)a.y - mu) * rs + (double)b.y)),
                         (float)(2.0 * (((double)a.z - mu) * rs + (double)b.z)),
                         (float)(2.0 * (((double)a.w - mu) * rs + (double)b.w)));
  reinterpret_cast<float4*>(x)[e4] = o;
}

// out_fp32 = (x - mu)*rstd
__global__ __launch_bounds__(256)
void k_norm_out(const float* __restrict__ x, const double* __restrict__ stats,
                float* __restrict__ out) {
  int e4 = blockIdx.x * 256 + threadIdx.x;
  double mu = stats[0], rs = stats[1];
  float4 v = reinterpret_cast<const float4*>(x)[e4];
  float4 o = make_float4((float)(((double)v.x - mu) * rs),
                         (float)(((double)v.y - mu) * rs),
                         (float)(((double)v.z - mu) * rs),
                         (float)(((double)v.w - mu) * rs));
  reinterpret_cast<float4*>(out)[e4] = o;
}

// ---------------- GEMM (fp32 in, fp64 accumulate): C = A[4096x1024] * B[1024x1024] ----
// 64x64 tile, BK=16, 256 threads, 4x4/thread.  LDS tiles stored as DOUBLE
// (converted once at staging — cvt is exact, so results are bit-identical to the
// per-k-cvt version while removing 8 v_cvt_f64_f32 per inner k).  B columns are
// swizzled (c + (c>>4)) to break the 4-way bank conflict of the 32B-stride reads.
// Register prefetch of the next k-slab hides global latency.
// scatter=1: write C to [B,H,T,HD] layout (for q/k/v); scatter=0: row-major.
#define SWZB(c) ((c) + ((c) >> 4))
__global__ __launch_bounds__(256)
void k_gemm(const float* __restrict__ A, const float* __restrict__ Bm,
            float* __restrict__ C, int scatter) {
  __shared__ double As[16][68];   // As[k][m]        (A reads broadcast per-ty: conflict-free)
  __shared__ double Bs[16][72];   // Bs[k][SWZB(n)]  (max index 66)
  int t  = threadIdx.x;
  int m0 = blockIdx.y * 64;
  int n0 = blockIdx.x * 64;
  int tx = t & 15, ty = t >> 4;
  int ar = t >> 2, ak = (t & 3) * 4;   // A: row 0..63, k-chunk
  int br = t >> 4, bc = (t & 15) * 4;  // B: k-row 0..15, col-chunk
  int sb = SWZB(bc);                   // bc%16 in {0,4,8,12} -> 4-group stays contiguous

  const float* Ap = &A[(size_t)(m0 + ar) * DDIM + ak];
  const float* Bp = &Bm[(size_t)br * DDIM + n0 + bc];
  float4 av = *reinterpret_cast<const float4*>(Ap);
  float4 bv = *reinterpret_cast<const float4*>(Bp);

  double acc[4][4] = {};
  int cA = ty * 4;
  int cB = SWZB(tx * 4);               // tx*4%16 in {0,4,8,12} -> contiguous 4-group

  for (int kk = 0; kk < DDIM; kk += 16) {
    __syncthreads();
    As[ak + 0][ar] = (double)av.x; As[ak + 1][ar] = (double)av.y;
    As[ak + 2][ar] = (double)av.z; As[ak + 3][ar] = (double)av.w;
    Bs[br][sb + 0] = (double)bv.x; Bs[br][sb + 1] = (double)bv.y;
    Bs[br][sb + 2] = (double)bv.z; Bs[br][sb + 3] = (double)bv.w;
    __syncthreads();

    if (kk + 16 < DDIM) {              // prefetch next slab into regs
      av = *reinterpret_cast<const float4*>(Ap + kk + 16);
      bv = *reinterpret_cast<const float4*>(Bp + (size_t)(kk + 16) * DDIM);
    }

    #pragma unroll
    for (int k = 0; k < 16; ++k) {
      double ad[4], bd[4];
      #pragma unroll
      for (int i = 0; i < 4; ++i) ad[i] = As[k][cA + i];
      #pragma unroll
      for (int j = 0; j < 4; ++j) bd[j] = Bs[k][cB + j];
      #pragma unroll
      for (int i = 0; i < 4; ++i)
        #pragma unroll
        for (int j = 0; j < 4; ++j)
          acc[i][j] += ad[i] * bd[j];
    }
  }

  #pragma unroll
  for (int i = 0; i < 4; ++i) {
    int r  = m0 + ty * 4 + i;
    int b  = r >> 10;           // batch
    int tp = r & 1023;          // seq pos
    int cb = n0 + tx * 4;       // head-aligned: cb&63 == tx*4
    float4 val = make_float4((float)acc[i][0], (float)acc[i][1],
                             (float)acc[i][2], (float)acc[i][3]);
    if (scatter) {
      int h = cb >> 6, d = cb & 63;
      *reinterpret_cast<float4*>(
          &C[((size_t)((b * NH + h) * TDIM + tp)) * HDIM + d]) = val;
    } else {
      *reinterpret_cast<float4*>(&C[(size_t)r * DDIM + cb]) = val;
    }
  }
}

// ---------------- attention: tiled flash-style, fp64 accumulate ----------------
// Transposed-score variant: for output row i, "query" = k[i], keys = q[j],
// values = v[j], j <= i.  Math is fp64 end-to-end, identical operation order to
// the round-1 kernel (bit-compatible).  Triangular load balance: block z handles
// i-tiles {z, 15-z} -> uniform 17 j-tile units/block, 512 blocks = 2/CU.
__global__ __launch_bounds__(256)
void k_attn_flash(const float* __restrict__ q, const float* __restrict__ k,
                  const float* __restrict__ v, float* __restrict__ attout) {
  int z  = blockIdx.x;           // 0..7
  int bh = blockIdx.y;           // b*16 + h
  int b  = bh >> 4, h = bh & 15;
  const float* qh = q + (size_t)bh * TDIM * HDIM;
  const float* kh = k + (size_t)bh * TDIM * HDIM;
  const float* vh = v + (size_t)bh * TDIM * HDIM;

  // pad 68 floats: float4 alignment (272 B % 16 == 0) + breaks bank conflicts
  __shared__ float Ks[64][68];   // K tile, transposed: Ks[d][i]
  __shared__ float Qs[64][68];   // Q tile, transposed: Qs[d][j]; reused as Pt[j][i]
  __shared__ float Vs[64][68];   // V tile, row-major:  Vs[j][d]

  int t  = threadIdx.x;
  int tx = t & 15, ty = t >> 4;  // thread owns i-rows ty*4+., cols tx*4+.

  for (int phase = 0; phase < 2; ++phase) {
    int it = phase ? (15 - z) : z;
    int i0 = it * 64;

    __syncthreads();             // prev phase's LDS fully consumed before restage

    // ---- stage K tile (transposed) ----
    #pragma unroll
    for (int itr = 0; itr < 4; ++itr) {
      int f = t + 256 * itr;
      int r = f >> 4, dc = (f & 15) * 4;
      float4 val = *reinterpret_cast<const float4*>(&kh[(size_t)(i0 + r) * HDIM + dc]);
      Ks[dc + 0][r] = val.x; Ks[dc + 1][r] = val.y;
      Ks[dc + 2][r] = val.z; Ks[dc + 3][r] = val.w;
    }

    double O[4][4] = {};
    double m[4], l[4];
    #pragma unroll
    for (int i = 0; i < 4; ++i) { m[i] = -1.0e300; l[i] = 0.0; }

    for (int jt = 0; jt <= it; ++jt) {
      int j0 = jt * 64;

      // ---- load Q,V tiles to regs (global, coalesced float4) ----
      float4 qv[4], vv[4];
      #pragma unroll
      for (int itr = 0; itr < 4; ++itr) {
        int f = t + 256 * itr;
        int r = f >> 4, dc = (f & 15) * 4;
        qv[itr] = *reinterpret_cast<const float4*>(&qh[(size_t)(j0 + r) * HDIM + dc]);
        vv[itr] = *reinterpret_cast<const float4*>(&vh[(size_t)(j0 + r) * HDIM + dc]);
      }
      __syncthreads();           // prev iteration's PV reads (Pt=Qs, Vs) done
      #pragma unroll
      for (int itr = 0; itr < 4; ++itr) {
        int f = t + 256 * itr;
        int r = f >> 4, dc = (f & 15) * 4;
        Qs[dc + 0][r] = qv[itr].x; Qs[dc + 1][r] = qv[itr].y;
        Qs[dc + 2][r] = qv[itr].z; Qs[dc + 3][r] = qv[itr].w;
        *reinterpret_cast<float4*>(&Vs[r][dc]) = vv[itr];
      }
      __syncthreads();

      // ---- S[4][4] = K_i . Q_j^T  (fp64, d ascending) ----
      double S[4][4] = {};
      #pragma unroll 16
      for (int d = 0; d < 64; ++d) {
        float4 kf = *reinterpret_cast<const float4*>(&Ks[d][ty * 4]);
        float4 qf = *reinterpret_cast<const float4*>(&Qs[d][tx * 4]);
        double kd[4] = {(double)kf.x, (double)kf.y, (double)kf.z, (double)kf.w};
        double qd[4] = {(double)qf.x, (double)qf.y, (double)qf.z, (double)qf.w};
        #pragma unroll
        for (int i = 0; i < 4; ++i)
          #pragma unroll
          for (int j = 0; j < 4; ++j)
            S[i][j] += kd[i] * qd[j];
      }

      // ---- scale + causal mask (diagonal tile only) ----
      double mloc[4];
      #pragma unroll
      for (int i = 0; i < 4; ++i) {
        #pragma unroll
        for (int j = 0; j < 4; ++j) {
          S[i][j] *= 0.125;
          if (jt == it && (tx * 4 + j) > (ty * 4 + i)) S[i][j] = -1.0e300;
        }
        mloc[i] = fmax(fmax(S[i][0], S[i][1]), fmax(S[i][2], S[i][3]));
      }
      #pragma unroll
      for (int xm = 1; xm < 16; xm <<= 1)
        #pragma unroll
        for (int i = 0; i < 4; ++i)
          mloc[i] = fmax(mloc[i], __shfl_xor(mloc[i], xm, 64));

      // ---- online softmax update (fp64) ----
      double p[4][4], tsum[4];
      #pragma unroll
      for (int i = 0; i < 4; ++i) {
        double mnew  = fmax(m[i], mloc[i]);
        double scale = exp(m[i] - mnew);
        m[i] = mnew;
        tsum[i] = 0.0;
        #pragma unroll
        for (int j = 0; j < 4; ++j) {
          p[i][j] = exp(S[i][j] - mnew);
          tsum[i] += p[i][j];
        }
        l[i] *= scale;
        #pragma unroll
        for (int j = 0; j < 4; ++j) O[i][j] *= scale;
      }
      #pragma unroll
      for (int xm = 1; xm < 16; xm <<= 1)
        #pragma unroll
        for (int i = 0; i < 4; ++i)
          tsum[i] += __shfl_xor(tsum[i], xm, 64);
      #pragma unroll
      for (int i = 0; i < 4; ++i) l[i] += tsum[i];

      __syncthreads();           // all done reading Qs; safe to overwrite with Pt
      // Pt[j][i] = p[i][j]  (fp32 round-trip — validated bit-compatible in r1)
      #pragma unroll
      for (int i = 0; i < 4; ++i)
        #pragma unroll
        for (int j = 0; j < 4; ++j)
          Qs[tx * 4 + j][ty * 4 + i] = (float)p[i][j];
      __syncthreads();

      // ---- O[4][4] += P . V  (fp64 accumulate) ----
      #pragma unroll 16
      for (int jl = 0; jl < 64; ++jl) {
        float4 pf = *reinterpret_cast<const float4*>(&Qs[jl][ty * 4]);
        float4 vf = *reinterpret_cast<const float4*>(&Vs[jl][tx * 4]);
        double pd[4] = {(double)pf.x, (double)pf.y, (double)pf.z, (double)pf.w};
        double vd[4] = {(double)vf.x, (double)vf.y, (double)vf.z, (double)vf.w};
        #pragma unroll
        for (int i = 0; i < 4; ++i)
          #pragma unroll
          for (int j = 0; j < 4; ++j)
            O[i][j] += pd[i] * vd[j];
      }
    }

    // ---- epilogue: out[b, i, h*64 + d] = O / l ----
    #pragma unroll
    for (int i = 0; i < 4; ++i) {
      int ig = i0 + ty * 4 + i;
      double inv = 1.0 / l[i];
      float4 o;
      o.x = (float)(O[i][0] * inv); o.y = (float)(O[i][1] * inv);
      o.z = (float)(O[i][2] * inv); o.w = (float)(O[i][3] * inv);
      *reinterpret_cast<float4*>(
          &attout[((size_t)(b * TDIM + ig)) * DDIM + h * HDIM + tx * 4]) = o;
    }
  }
}

// ---------------- launcher ----------------
extern "C" void kernel_launch(void* const* d_in, const int* in_sizes, int n_in,
                              void* d_out, int out_size, void* d_ws, size_t ws_size,
                              hipStream_t stream) {
  (void)in_sizes; (void)n_in; (void)out_size; (void)ws_size;
  const int*   idx = (const int*)d_in[0];
  const float* tok = (const float*)d_in[1];
  const float* pos = (const float*)d_in[2];
  const float* wq  = (const float*)d_in[3];
  const float* wk  = (const float*)d_in[4];
  const float* wv  = (const float*)d_in[5];
  const float* wo  = (const float*)d_in[6];
  // d_in[7..9] (w_in, w_out, lm_head) are dead code in the reference
  float* out = (float*)d_out;

  float* ws   = (float*)d_ws;
  float* x    = ws;                 // [4096,1024]; also reused for att
  float* xn   = x   + NELEM;        // [4096,1024]  (also t1 = xn+proj)
  float* q    = xn  + NELEM;        // [B,H,T,HD]   (also reused for proj)
  float* k    = q   + NELEM;        // [B,H,T,HD]
  float* v    = k   + NELEM;        // [B,H,T,HD]
  float* att  = x;                  // alias: x dead between norm(x) and combine
  float* proj = q;                  // alias: q dead once att computed
  double* part  = (double*)(v + NELEM);   // [4096*2] fp64 partials (64 KB)
  double* stats = part + 8192;            // [2] fp64 (mu, rstd)

  dim3 ggemm(DDIM / 64, NTOK / 64);   // (16, 64) = 1024 blocks, 4/CU
  dim3 gattn(8, BB * NH);             // (8, 64) = 512 blocks, paired i-tiles

  k_embed<<<4096, 256, 0, stream>>>(idx, tok, pos, x);

  for (int l = 0; l < NLAYER; ++l) {
    // xn = ln_all(x)
    k_reduce1<<<4096, 256, 0, stream>>>(x, part);
    k_reduce2<<<1, 1024, 0, stream>>>(part, stats);
    k_norm4<<<4096, 256, 0, stream>>>(x, stats, xn);
    // q,k,v (scattered to [B,H,T,HD])
    k_gemm<<<ggemm, 256, 0, stream>>>(xn, wq, q, 1);
    k_gemm<<<ggemm, 256, 0, stream>>>(xn, wk, k, 1);
    k_gemm<<<ggemm, 256, 0, stream>>>(xn, wv, v, 1);
    // attention -> att [4096,1024] (x-alias; x is dead here)
    k_attn_flash<<<gattn, 256, 0, stream>>>(q, k, v, att);
    // proj = att @ Wo   (plain layout; writes into q-alias)
    k_gemm<<<ggemm, 256, 0, stream>>>(att, wo, proj, 0);
    // t1 = xn + proj (in place in xn)
    k_add4<<<4096, 256, 0, stream>>>(xn, proj);
    // x = 2*(ln_all(t1) + proj)
    k_reduce1<<<4096, 256, 0, stream>>>(xn, part);
    k_reduce2<<<1, 1024, 0, stream>>>(part, stats);
    k_combine4<<<4096, 256, 0, stream>>>(xn, proj, stats, x);
  }

  // out = fp32(ln_all(x))
  k_reduce1<<<4096, 256, 0, stream>>>(x, part);
  k_reduce2<<<1, 1024, 0, stream>>>(part, stats);
  k_norm_out<<<4096, 256, 0, stream>>>(x, stats, out);
}